// Round 8
// baseline (28.761 us; speedup 1.0000x reference)
//
#include <hip/hip_runtime.h>

// TransformLayer: per-pixel reprojection, B=8 H=768 W=1024, fp32.
// Memory-bound; output (100.7 MB) fits in 256MB LLC -> allocating stores.
// R1: raw v_rcp/v_sqrt + FMA contraction (33->25.2 us).
// R3: nontemporal STORES -> 76.5 us REGRESSION (HBM write amplification). Reverted.
// R5: 8 px/thread, two wave-coalesced float4 groups (24.9 us).
// R6: algebraic cut (den-cancellation, stable ratio, divide cancels) -> 24.67 us:
//     ~1% => NOT VALU-bound; memory system at ~8.3 B/cyc/CU vs 10-11 achievable.
// R7: 16 px/thread, 4 groups each = one full row (x0/xn shared across groups,
//     only row terms update); all 4 input loads prefetched; nontemporal LOADS
//     (no-allocate) keep inv_depth out of L2 so stores own it.

#define EPSF 1e-06f

typedef float f32x4 __attribute__((ext_vector_type(4)));

constexpr int Bc = 8;
constexpr int Hc = 768;
constexpr int Wc = 1024;
constexpr int HW = Hc * Wc;          // 786432
constexpr int THREADS = 256;
constexpr int NGROUPS = 4;
constexpr int GROUP_PIX = THREADS * 4;                    // 1024 = one row
constexpr int BLOCK_PIX = GROUP_PIX * NGROUPS;            // 4096
constexpr int BLOCKS_X = HW / BLOCK_PIX;                  // 192

__device__ __forceinline__ float frcp(float x)   { return __builtin_amdgcn_rcpf(x); }
__device__ __forceinline__ float fsqrtf_(float x){ return __builtin_amdgcn_sqrtf(x); }

__global__ __launch_bounds__(THREADS)
void transform_layer_kernel(const float* __restrict__ inv_depth,
                            const float* __restrict__ transform,
                            const float* __restrict__ calib_i,
                            const float* __restrict__ lam_i_p,
                            const float* __restrict__ calib_j,
                            const float* __restrict__ lam_j_p,
                            float* __restrict__ out)
{
    const int b     = blockIdx.y;                         // batch (wave-uniform)
    const int pbase = blockIdx.x * BLOCK_PIX + threadIdx.x * 4;
    const int yrow0 = pbase >> 10;                        // row of group 0
    const int x0    = pbase & (Wc - 1);                   // same for ALL groups

    // Per-batch params (uniform addresses -> scalar loads)
    const float* T = transform + b * 16;
    const float t00=T[0], t01=T[1], t02=T[2], t03=T[3];
    const float t10=T[4], t11=T[5], t12=T[6], t13=T[7];
    const float t20=T[8], t21=T[9], t22=T[10], t23=T[11];
    const float t30=T[12], t31=T[13], t32=T[14], t33=T[15];
    const float fx  = calib_i[b*4+0], fy  = calib_i[b*4+1];
    const float cx  = calib_i[b*4+2], cy  = calib_i[b*4+3];
    const float li  = lam_i_p[b];
    const float fxj = calib_j[b*4+0], fyj = calib_j[b*4+1];
    const float cxj = calib_j[b*4+2], cyj = calib_j[b*4+3];
    const float lj  = lam_j_p[b];
    const float lj4 = 4.0f * lj;
    const float fxj2 = 2.0f * fxj;
    const float fyj2 = 2.0f * fyj;

    const float rfx = frcp(fx);
    const float rfy = frcp(fy);

    const float* idb = inv_depth + (size_t)b * HW;
    float*       ub  = out + (size_t)b * 3 * HW;
    float*       mb  = out + (size_t)Bc * 3 * HW + (size_t)b * HW;

    // x-dependent terms: identical across the 4 groups (group stride == W)
    const float xnb = ((float)x0 - cx) * rfx;
    float xn_[4], lx2_[4];
#pragma unroll
    for (int i = 0; i < 4; ++i) {
        xn_[i]  = fmaf((float)i, rfx, xnb);
        lx2_[i] = li * (xn_[i] * xn_[i]);                 // den = lx2 + den_y
    }

    // Prefetch all 4 input vectors (nontemporal: no L2/L1 allocate)
    f32x4 idv_[NGROUPS];
#pragma unroll
    for (int g = 0; g < NGROUPS; ++g)
        idv_[g] = __builtin_nontemporal_load(
                      reinterpret_cast<const f32x4*>(idb + pbase + g * GROUP_PIX));

#pragma unroll
    for (int g = 0; g < NGROUPS; ++g) {
        const int p0 = pbase + g * GROUP_PIX;
        // row terms for this group
        const float yn    = ((float)(yrow0 + g) - cy) * rfy;
        const float den_y = fmaf(li, yn * yn, 1.0f);
        const float py_a = t01 * yn;
        const float py_b = t11 * yn;
        const float py_c = t21 * yn;
        const float py_d = t31 * yn;

        const f32x4 idv = idv_[g];
        float u4[4], v4[4], rho4[4], m4[4];

#pragma unroll
        for (int i = 0; i < 4; ++i) {
            const float xn  = xn_[i];
            const float den = lx2_[i] + den_y;
            const bool valid_norm = den > EPSF;
            const float X3 = idv[i];
            // homogeneous transform scaled by den: [xn, yn, den, X3*den]
            const float ap = fmaf(t00, xn, fmaf(fmaf(t03, X3, t02), den, py_a));
            const float bp = fmaf(t10, xn, fmaf(fmaf(t13, X3, t12), den, py_b));
            const float cp = fmaf(t20, xn, fmaf(fmaf(t23, X3, t22), den, py_c));
            const float dp = fmaf(t30, xn, fmaf(fmaf(t33, X3, t32), den, py_d));
            // perspective: cz=c' valid, cz=den invalid (matches ref branches)
            const bool  mask_src = cp > EPSF * den;
            const float cz  = mask_src ? cp : den;
            const float rcz = frcp(cz);
            const float rho = dp * rcz;
            // redistort, disc scaled by cz^2
            const float q     = fmaf(ap, ap, bp * bp);
            const float discp = fmaf(-lj4, q, cz * cz);
            const bool  valid_un = discp >= 0.0f;
            const float sq = fsqrtf_(fmaxf(discp, 0.0f));
            const float denom = cz + (valid_un ? sq : cz);
            const float gg = frcp(denom);
            const float u = fmaf(fxj2, ap * gg, cxj);
            const float v = fmaf(fyj2, bp * gg, cyj);
            const bool inb = (u >= 0.0f) & (u <= (float)(Wc - 1)) &
                             (v >= 0.0f) & (v <= (float)(Hc - 1));
            const bool mask = mask_src & inb & valid_norm & valid_un;

            u4[i] = u; v4[i] = v; rho4[i] = rho;
            m4[i] = mask ? 1.0f : 0.0f;
        }

        // Wave-coalesced float4 stores: 3 x_proj planes + mask plane
        const f32x4 uv   = { u4[0], u4[1], u4[2], u4[3] };
        const f32x4 vv   = { v4[0], v4[1], v4[2], v4[3] };
        const f32x4 rhov = { rho4[0], rho4[1], rho4[2], rho4[3] };
        const f32x4 mv   = { m4[0], m4[1], m4[2], m4[3] };
        *reinterpret_cast<f32x4*>(ub + p0)          = uv;
        *reinterpret_cast<f32x4*>(ub + HW + p0)     = vv;
        *reinterpret_cast<f32x4*>(ub + 2 * HW + p0) = rhov;
        *reinterpret_cast<f32x4*>(mb + p0)          = mv;
    }
}

extern "C" void kernel_launch(void* const* d_in, const int* in_sizes, int n_in,
                              void* d_out, int out_size, void* d_ws, size_t ws_size,
                              hipStream_t stream) {
    const float* inv_depth = (const float*)d_in[0];
    const float* transform = (const float*)d_in[1];
    const float* calib_i   = (const float*)d_in[2];
    const float* lam_i     = (const float*)d_in[3];
    const float* calib_j   = (const float*)d_in[4];
    const float* lam_j     = (const float*)d_in[5];
    // d_in[6] = non_rigid, always 0 for this problem (rigid einsum path)
    float* out = (float*)d_out;

    dim3 grid(BLOCKS_X, Bc);
    dim3 block(THREADS);
    transform_layer_kernel<<<grid, block, 0, stream>>>(
        inv_depth, transform, calib_i, lam_i, calib_j, lam_j, out);
}

// Round 9
// 24.647 us; speedup vs baseline: 1.1669x; 1.1669x over previous
//
#include <hip/hip_runtime.h>

// TransformLayer: per-pixel reprojection, B=8 H=768 W=1024, fp32.
// Memory-bound; output (100.7 MB) fits in 256MB LLC -> allocating stores.
// R1: raw v_rcp/v_sqrt + FMA contraction (33->25.2 us).
// R3: nontemporal STORES -> 76.5 us REGRESSION (HBM write amplification). Reverted.
// R5: 8 px/thread, two wave-coalesced float4 groups (24.9 us).
// R6: algebraic cut (den-cancellation, stable ratio) -> 24.67 us. NOT VALU-bound.
// R7: nt LOADS + 16px/thread -> 28.8 us REGRESSION (cache bypass costs again).
// R8: R6 base; both loads hoisted to entry, both groups computed, then all 8
//     stores issued plane-major (stream-batched). No numeric changes.

#define EPSF 1e-06f

typedef float f32x4 __attribute__((ext_vector_type(4)));

constexpr int Bc = 8;
constexpr int Hc = 768;
constexpr int Wc = 1024;
constexpr int HW = Hc * Wc;          // 786432
constexpr int THREADS = 256;
constexpr int NG = 2;                // 2 coalesced float4 groups
constexpr int GROUP_PIX = THREADS * 4;                    // 1024
constexpr int BLOCK_PIX = GROUP_PIX * NG;                 // 2048
constexpr int BLOCKS_X = HW / BLOCK_PIX;                  // 384

__device__ __forceinline__ float frcp(float x)   { return __builtin_amdgcn_rcpf(x); }
__device__ __forceinline__ float fsqrtf_(float x){ return __builtin_amdgcn_sqrtf(x); }

__global__ __launch_bounds__(THREADS)
void transform_layer_kernel(const float* __restrict__ inv_depth,
                            const float* __restrict__ transform,
                            const float* __restrict__ calib_i,
                            const float* __restrict__ lam_i_p,
                            const float* __restrict__ calib_j,
                            const float* __restrict__ lam_j_p,
                            float* __restrict__ out)
{
    const int b     = blockIdx.y;                         // batch (wave-uniform)
    const int pbase = blockIdx.x * BLOCK_PIX + threadIdx.x * 4;

    const float* idb = inv_depth + (size_t)b * HW;
    float*       ub  = out + (size_t)b * 3 * HW;
    float*       mb  = out + (size_t)Bc * 3 * HW + (size_t)b * HW;

    // Issue BOTH input loads immediately (HBM latency hides under param loads + compute)
    f32x4 idv_[NG];
#pragma unroll
    for (int g = 0; g < NG; ++g)
        idv_[g] = *reinterpret_cast<const f32x4*>(idb + pbase + g * GROUP_PIX);

    // Per-batch params (uniform addresses -> scalar loads)
    const float* T = transform + b * 16;
    const float t00=T[0], t01=T[1], t02=T[2], t03=T[3];
    const float t10=T[4], t11=T[5], t12=T[6], t13=T[7];
    const float t20=T[8], t21=T[9], t22=T[10], t23=T[11];
    const float t30=T[12], t31=T[13], t32=T[14], t33=T[15];
    const float fx  = calib_i[b*4+0], fy  = calib_i[b*4+1];
    const float cx  = calib_i[b*4+2], cy  = calib_i[b*4+3];
    const float li  = lam_i_p[b];
    const float fxj = calib_j[b*4+0], fyj = calib_j[b*4+1];
    const float cxj = calib_j[b*4+2], cyj = calib_j[b*4+3];
    const float lj  = lam_j_p[b];
    const float lj4 = 4.0f * lj;
    const float fxj2 = 2.0f * fxj;
    const float fyj2 = 2.0f * fyj;

    const float rfx = frcp(fx);
    const float rfy = frcp(fy);

    f32x4 uo[NG], vo[NG], ro[NG], mo[NG];

#pragma unroll
    for (int g = 0; g < NG; ++g) {
        const int p0   = pbase + g * GROUP_PIX;
        const int yrow = p0 >> 10;
        const int x0   = p0 & (Wc - 1);

        const float yn  = ((float)yrow - cy) * rfy;
        const float xnb = ((float)x0 - cx) * rfx;
        const float den_y = fmaf(li, yn * yn, 1.0f);
        const float py_a = t01 * yn;
        const float py_b = t11 * yn;
        const float py_c = t21 * yn;
        const float py_d = t31 * yn;

        const f32x4 idv = idv_[g];

#pragma unroll
        for (int i = 0; i < 4; ++i) {
            const float xn  = fmaf((float)i, rfx, xnb);
            const float den = fmaf(li, xn * xn, den_y);
            const bool valid_norm = den > EPSF;
            const float X3 = idv[i];
            // homogeneous transform scaled by den: [xn, yn, den, X3*den]
            const float ap = fmaf(t00, xn, fmaf(fmaf(t03, X3, t02), den, py_a));
            const float bp = fmaf(t10, xn, fmaf(fmaf(t13, X3, t12), den, py_b));
            const float cp = fmaf(t20, xn, fmaf(fmaf(t23, X3, t22), den, py_c));
            const float dp = fmaf(t30, xn, fmaf(fmaf(t33, X3, t32), den, py_d));
            // perspective: cz=c' valid, cz=den invalid (matches ref branches)
            const bool  mask_src = cp > EPSF * den;
            const float cz  = mask_src ? cp : den;
            const float rcz = frcp(cz);
            const float rho = dp * rcz;
            // redistort, disc scaled by cz^2
            const float q     = fmaf(ap, ap, bp * bp);
            const float discp = fmaf(-lj4, q, cz * cz);
            const bool  valid_un = discp >= 0.0f;
            const float sq = fsqrtf_(fmaxf(discp, 0.0f));
            const float denom = cz + (valid_un ? sq : cz);
            const float gg = frcp(denom);
            const float u = fmaf(fxj2, ap * gg, cxj);
            const float v = fmaf(fyj2, bp * gg, cyj);
            const bool inb = (u >= 0.0f) & (u <= (float)(Wc - 1)) &
                             (v >= 0.0f) & (v <= (float)(Hc - 1));
            const bool mask = mask_src & inb & valid_norm & valid_un;

            uo[g][i] = u; vo[g][i] = v; ro[g][i] = rho;
            mo[g][i] = mask ? 1.0f : 0.0f;
        }
    }

    // Plane-major store batch: consecutive instructions hit the same stream
    const int p0 = pbase;
    const int p1 = pbase + GROUP_PIX;
    *reinterpret_cast<f32x4*>(ub + p0)          = uo[0];
    *reinterpret_cast<f32x4*>(ub + p1)          = uo[1];
    *reinterpret_cast<f32x4*>(ub + HW + p0)     = vo[0];
    *reinterpret_cast<f32x4*>(ub + HW + p1)     = vo[1];
    *reinterpret_cast<f32x4*>(ub + 2 * HW + p0) = ro[0];
    *reinterpret_cast<f32x4*>(ub + 2 * HW + p1) = ro[1];
    *reinterpret_cast<f32x4*>(mb + p0)          = mo[0];
    *reinterpret_cast<f32x4*>(mb + p1)          = mo[1];
}

extern "C" void kernel_launch(void* const* d_in, const int* in_sizes, int n_in,
                              void* d_out, int out_size, void* d_ws, size_t ws_size,
                              hipStream_t stream) {
    const float* inv_depth = (const float*)d_in[0];
    const float* transform = (const float*)d_in[1];
    const float* calib_i   = (const float*)d_in[2];
    const float* lam_i     = (const float*)d_in[3];
    const float* calib_j   = (const float*)d_in[4];
    const float* lam_j     = (const float*)d_in[5];
    // d_in[6] = non_rigid, always 0 for this problem (rigid einsum path)
    float* out = (float*)d_out;

    dim3 grid(BLOCKS_X, Bc);
    dim3 block(THREADS);
    transform_layer_kernel<<<grid, block, 0, stream>>>(
        inv_depth, transform, calib_i, lam_i, calib_j, lam_j, out);
}